// Round 5
// baseline (24.119 us; speedup 1.0000x reference)
//
#include <hip/hip_runtime.h>
#include <hip/hip_bf16.h>

// out[t,b,e] = sum_m (A[m,t,b,e] + i*B[m,t,b,e]) * w[b,t,m],  A=d_in[0], B=d_in[1]
// M=3, T=128, B=64, E=512.
// Output: bf16, flat interleaved pairs [T,B,E,2], out_size = 8,388,608.
// Evidence (r0 max|ref|=15.5; r2/r3 err = 22.6875 = 15.5*sqrt(2) exactly = max|re-im|):
// slot 2k must hold the d_in[1]-derived component, slot 2k+1 the d_in[0]-derived one.
#define MM 3
#define TT 128
#define BB 64
#define EE 512

// round-to-nearest-even float32 -> bf16 (low 16 bits of result)
static __device__ __forceinline__ unsigned int f2bf(float x) {
    unsigned int u = __float_as_uint(x);
    return (u + 0x7FFFu + ((u >> 16) & 1u)) >> 16;
}

__global__ __launch_bounds__(256) void qmix_kernel(
    const float* __restrict__ A, const float* __restrict__ Bv,
    const float* __restrict__ w, uint4* __restrict__ out)
{
    // Each thread: 4 consecutive e values. 128 threads per (t,b) row.
    const int idx = blockIdx.x * blockDim.x + threadIdx.x;   // 0 .. T*B*E/4-1
    const int e4  = idx & (EE / 4 - 1);                      // 0..127
    const int tb  = idx >> 7;                                // t*B + b
    const int b   = tb & (BB - 1);
    const int t   = tb >> 6;

    // weights[b][t][m] — 96 KB, cache-resident, uniform per (t,b)
    const int wbase = (b * TT + t) * MM;
    const float w0 = w[wbase + 0];
    const float w1 = w[wbase + 1];
    const float w2 = w[wbase + 2];

    const size_t TBE  = (size_t)TT * BB * EE;                // 4,194,304
    const size_t base = (size_t)tb * EE + (size_t)e4 * 4;    // element index

    const float4 a0 = *(const float4*)(A + base);
    const float4 a1 = *(const float4*)(A + base + TBE);
    const float4 a2 = *(const float4*)(A + base + 2 * TBE);
    const float4 b0 = *(const float4*)(Bv + base);
    const float4 b1 = *(const float4*)(Bv + base + TBE);
    const float4 b2 = *(const float4*)(Bv + base + 2 * TBE);

    // per element: p = A-mix, q = B-mix
    const float p0 = a0.x * w0 + a1.x * w1 + a2.x * w2;
    const float q0 = b0.x * w0 + b1.x * w1 + b2.x * w2;
    const float p1 = a0.y * w0 + a1.y * w1 + a2.y * w2;
    const float q1 = b0.y * w0 + b1.y * w1 + b2.y * w2;
    const float p2 = a0.z * w0 + a1.z * w1 + a2.z * w2;
    const float q2 = b0.z * w0 + b1.z * w1 + b2.z * w2;
    const float p3 = a0.w * w0 + a1.w * w1 + a2.w * w2;
    const float q3 = b0.w * w0 + b1.w * w1 + b2.w * w2;

    // SWAPPED slot order (see header): low address slot = B-mix, high = A-mix.
    uint4 pk;
    pk.x = f2bf(q0) | (f2bf(p0) << 16);
    pk.y = f2bf(q1) | (f2bf(p1) << 16);
    pk.z = f2bf(q2) | (f2bf(p2) << 16);
    pk.w = f2bf(q3) | (f2bf(p3) << 16);

    out[tb * (EE / 4) + e4] = pk;   // byte offset = base*4, 16B aligned
}

extern "C" void kernel_launch(void* const* d_in, const int* in_sizes, int n_in,
                              void* d_out, int out_size, void* d_ws, size_t ws_size,
                              hipStream_t stream) {
    const float* A  = (const float*)d_in[0];
    const float* Bv = (const float*)d_in[1];
    const float* w  = (const float*)d_in[2];   // weights [B,T,M]
    uint4* out = (uint4*)d_out;

    const int total_threads = TT * BB * EE / 4;  // 1,048,576
    const int block = 256;
    const int grid  = total_threads / block;     // 4096
    qmix_kernel<<<grid, block, 0, stream>>>(A, Bv, w, out);
}